// Round 18
// baseline (137.520 us; speedup 1.0000x reference)
//
#include <hip/hip_runtime.h>

#define N_NODES 50000
#define N_EDGES 600000
#define E_TOT   650000   // edges + self loops
#define EBLK    2344     // ceil(N_EDGES/256) edge chunks
#define NCLS    8        // dst classes == XCDs; class c handles dst&7==c
#define GBLK    391      // ceil(N_NODES/128) gemm blocks
#define ZBLK    196      // ceil(N_NODES/256) init blocks
#define MAXD    64       // ELL stride; max in-degree ~ Poisson(12)+1 << 64

typedef __attribute__((ext_vector_type(8))) short short8;
typedef __attribute__((ext_vector_type(4))) float f32x4;

__device__ inline short f2bf(float f) {           // round-to-nearest-even f32->bf16
  union { float f; unsigned u; } v; v.f = f;
  unsigned r = (v.u + 0x7FFFu + ((v.u >> 16) & 1u)) >> 16;
  return (short)r;
}
__device__ inline float bf2f(short u) {
  union { unsigned u; float f; } v; v.u = ((unsigned)(unsigned short)u) << 16;
  return v.f;
}

// ---------------------------------------------------------------- init: self-loop prefill + W prep (one launch)
// degp = line-padded counters. blocks [0, ZBLK): degp[i<<4]=1; ell[i*MAXD]=i.
// blocks [ZBLK, ZBLK+16): transpose-convert Wl1|Wr1 f32 [128k][128c] -> bf16 [256c][128k]

__global__ __launch_bounds__(256) void init_kernel(
    int* __restrict__ degp, unsigned short* __restrict__ ell,
    const float* __restrict__ Wl, const float* __restrict__ Wr, short* __restrict__ Wbf) {
  int b = blockIdx.x;
  if (b < ZBLK) {
    int i = b * 256 + threadIdx.x;
    if (i < N_NODES) {
      degp[i << 4] = 1;
      ell[i * MAXD] = (unsigned short)i;
    }
  } else {
    int gid = (b - ZBLK) * 256 + threadIdx.x;   // 4096 threads: 256 cols x 16 k-chunks
    int c = gid >> 4, k8 = (gid & 15) * 8;
    const float* W = (c < 128) ? Wl : Wr;
    int cc = c & 127;
    short8 o;
    #pragma unroll
    for (int j = 0; j < 8; ++j) o[j] = f2bf(W[(size_t)(k8 + j) * 128 + cc]);
    *(short8*)(Wbf + (size_t)c * 128 + k8) = o;
  }
}

// ---------------------------------------------------------------- layer 1 GEMM + XCD-partitioned ELL build
// blocks [0, GBLK): LDS-FREE MFMA GEMM (A in registers, B from L2-resident Wbf)
// blocks [GBLK, GBLK + NCLS*EBLK): scatter. Block class c = (b-GBLK)&7 processes
// ONLY edges with dst&7==c. Round-robin blockIdx->XCD maps each class to one
// XCD => its live ELL/counter lines (~1.2 MB) stay L2-resident, written back once.

__global__ __launch_bounds__(256) void gemm_build(
    const float* __restrict__ x, const short* __restrict__ Wbf,
    const float* __restrict__ bl, const float* __restrict__ br,
    short* __restrict__ xl, short* __restrict__ xr,
    const int* __restrict__ ei, int* __restrict__ degp, unsigned short* __restrict__ ell) {
  int t = threadIdx.x;

  if (blockIdx.x >= GBLK) {            // ---- partitioned edge scatter (no LDS)
    int b2 = blockIdx.x - GBLK;
    int cls = b2 & (NCLS - 1);
    int e = (b2 >> 3) * 256 + t;
    if (e < N_EDGES) {
      int d = ei[N_EDGES + e];
      if ((d & (NCLS - 1)) == cls) {
        int s = ei[e];
        int pos = atomicAdd(&degp[d << 4], 1);
        ell[d * MAXD + pos] = (unsigned short)s;
      }
    }
    return;
  }

  // ---- GEMM part
  int row0 = blockIdx.x * 128;
  int w = t >> 6, lane = t & 63;
  int wm = (w >> 1) * 64, wn = (w & 1) * 64;
  int lr = lane & 15, lk = (lane >> 4) * 8;

  // A fragments: rows wm+m*16+lr, k = ks*32+lk..+8, f32 -> bf16 inline.
  short8 af[4][4];                     // [ks][m]
  #pragma unroll
  for (int ks = 0; ks < 4; ++ks) {
    #pragma unroll
    for (int m = 0; m < 4; ++m) {
      int gr = row0 + wm + m * 16 + lr;
      gr = gr < N_NODES ? gr : N_NODES - 1;
      const float* p = x + (size_t)gr * 128 + ks * 32 + lk;
      f32x4 a = *(const f32x4*)p, b = *(const f32x4*)(p + 4);
      short8 o;
      o[0] = f2bf(a.x); o[1] = f2bf(a.y); o[2] = f2bf(a.z); o[3] = f2bf(a.w);
      o[4] = f2bf(b.x); o[5] = f2bf(b.y); o[6] = f2bf(b.z); o[7] = f2bf(b.w);
      af[ks][m] = o;
    }
  }

  #pragma unroll
  for (int hb = 0; hb < 2; ++hb) {
    f32x4 acc[4][4];
    #pragma unroll
    for (int m = 0; m < 4; ++m)
      #pragma unroll
      for (int n = 0; n < 4; ++n) acc[m][n] = (f32x4){0.f, 0.f, 0.f, 0.f};

    #pragma unroll
    for (int ks = 0; ks < 4; ++ks) {
      short8 bfr[4];
      #pragma unroll
      for (int n = 0; n < 4; ++n) {
        int col = hb * 128 + wn + n * 16 + lr;
        bfr[n] = *(const short8*)(Wbf + (size_t)col * 128 + ks * 32 + lk);
      }
      #pragma unroll
      for (int m = 0; m < 4; ++m)
        #pragma unroll
        for (int n = 0; n < 4; ++n)
          acc[m][n] = __builtin_amdgcn_mfma_f32_16x16x32_bf16(af[ks][m], bfr[n], acc[m][n], 0, 0, 0);
    }

    const float* B0 = hb ? br : bl;
    short* O = hb ? xr : xl;
    int orow = (lane >> 4) * 4;
    #pragma unroll
    for (int n = 0; n < 4; ++n) {
      int col = wn + n * 16 + lr;
      float bv = B0[col];
      #pragma unroll
      for (int m = 0; m < 4; ++m) {
        #pragma unroll
        for (int r = 0; r < 4; ++r) {
          int grow = row0 + wm + m * 16 + orow + r;
          if (grow < N_NODES) O[(size_t)grow * 128 + col] = f2bf(acc[m][n][r] + bv);
        }
      }
    }
  }
}

// ---------------------------------------------------------------- layer 1 attention+aggregation fused with layer-2 GEMV
// 16 lanes per node. Per 8-edge tile: gathers go global->LDS via
// global_load_lds (per-lane global addr, wave-uniform LDS dest, zero VGPR for
// in-flight rows). Wave-private LDS slots: no __syncthreads, just vmcnt.

__global__ __launch_bounds__(256) void agg1_fused(
    const short* __restrict__ xl1, const short* __restrict__ xr1,
    const float* __restrict__ att, const float* __restrict__ bias,
    const float* __restrict__ Wl2, const float* __restrict__ bl2,
    const float* __restrict__ Wr2, const float* __restrict__ br2,
    const int* __restrict__ degp, const unsigned short* __restrict__ ell,
    float* __restrict__ xl2, float* __restrict__ xr2) {
  __shared__ short sbuf[4][8][512];    // [wave][slot][64 lanes x 8 shorts] = 32 KB
  int gid = blockIdx.x * 256 + threadIdx.x;
  int node = gid >> 4;                 // grid exact: 3125 blocks * 16 nodes
  int t = threadIdx.x;
  int wid = t >> 6, lane = t & 63;
  int L = lane & 15;
  int gbase = lane & 48;               // wave-lane base of this 16-lane group

  short8 xr8 = *(const short8*)(xr1 + (size_t)node * 128 + L * 8);
  float xr[8], at[8];
  #pragma unroll
  for (int r = 0; r < 8; ++r) xr[r] = bf2f(xr8[r]);
  *(float4*)(at)     = *(const float4*)(att + L * 8);
  *(float4*)(at + 4) = *(const float4*)(att + L * 8 + 4);

  float m = -1e30f, denom = 0.f;
  float acc[8];
  #pragma unroll
  for (int r = 0; r < 8; ++r) acc[r] = 0.f;

  int p1 = degp[node << 4];
  const unsigned short* erow = ell + (size_t)node * MAXD;

  for (int base = 0; base < p1; base += 8) {
    // ONE coalesced index load: lane L holds edge (base+L)'s src for its node
    int pE = base + L;
    int myidx = erow[pE < p1 ? pE : p1 - 1];
    // 8 gathers global->LDS, all in flight, zero VGPR held
    #pragma unroll
    for (int j = 0; j < 8; ++j) {
      int ij = __shfl(myidx, gbase + j);
      const short* gp = xl1 + (size_t)ij * 128 + L * 8;
      __builtin_amdgcn_global_load_lds(
          (const __attribute__((address_space(1))) void*)gp,
          (__attribute__((address_space(3))) void*)&sbuf[wid][j][0],
          16, 0, 0);
    }
    asm volatile("s_waitcnt vmcnt(0)" ::: "memory");
    __builtin_amdgcn_sched_barrier(0);

    // 8 alpha dots (read own 16B slice back from LDS)
    float pa[8];
    #pragma unroll
    for (int j = 0; j < 8; ++j) {
      short8 v = *(const short8*)(&sbuf[wid][j][lane * 8]);
      float s = 0.f;
      #pragma unroll
      for (int r = 0; r < 8; ++r) {
        float e = bf2f(v[r]) + xr[r];
        e = fmaxf(e, 0.2f * e);          // leaky_relu 0.2, exact
        s = fmaf(e, at[r], s);
      }
      pa[j] = s;
    }
    // pipelined shuffle reductions (24 independent DS ops)
    #pragma unroll
    for (int st = 1; st < 8; st <<= 1) {
      #pragma unroll
      for (int j = 0; j < 8; ++j) pa[j] += __shfl_xor(pa[j], st);
    }
    // mask padded slots branchlessly (exp underflows to exact 0)
    #pragma unroll
    for (int j = 0; j < 8; ++j) pa[j] = (base + j < p1) ? pa[j] : -1e30f;
    // ONE online-softmax fold per tile
    float bm = pa[0];
    #pragma unroll
    for (int j = 1; j < 8; ++j) bm = fmaxf(bm, pa[j]);
    float mnew  = fmaxf(m, bm);
    float scale = __expf(m - mnew);
    float wgt[8], dsum = 0.f;
    #pragma unroll
    for (int j = 0; j < 8; ++j) { wgt[j] = __expf(pa[j] - mnew); dsum += wgt[j]; }
    denom = denom * scale + dsum;
    #pragma unroll
    for (int r = 0; r < 8; ++r) acc[r] *= scale;
    #pragma unroll
    for (int j = 0; j < 8; ++j) {
      short8 v = *(const short8*)(&sbuf[wid][j][lane * 8]);
      #pragma unroll
      for (int r = 0; r < 8; ++r) acc[r] = fmaf(wgt[j], bf2f(v[r]), acc[r]);
    }
    m = mnew;
  }

  float inv = 1.f / (denom + 1e-16f);
  float o[8];
  #pragma unroll
  for (int r = 0; r < 8; ++r) {
    float v = acc[r] * inv + bias[L * 8 + r];
    o[r] = fmaxf(v, 0.01f * v);         // post-layer LeakyReLU(0.01), exact
  }
  // fused layer-2 linear: lane L holds h[L*8 .. L*8+7]
  float pl[4] = {0.f, 0.f, 0.f, 0.f}, pr[4] = {0.f, 0.f, 0.f, 0.f};
  #pragma unroll
  for (int r = 0; r < 8; ++r) {
    float4 wl = *(const float4*)(Wl2 + (size_t)(L * 8 + r) * 4);
    float4 wr = *(const float4*)(Wr2 + (size_t)(L * 8 + r) * 4);
    pl[0] += o[r] * wl.x;  pl[1] += o[r] * wl.y;  pl[2] += o[r] * wl.z;  pl[3] += o[r] * wl.w;
    pr[0] += o[r] * wr.x;  pr[1] += o[r] * wr.y;  pr[2] += o[r] * wr.z;  pr[3] += o[r] * wr.w;
  }
  #pragma unroll
  for (int off = 1; off < 16; off <<= 1) {
    #pragma unroll
    for (int c = 0; c < 4; ++c) {
      pl[c] += __shfl_xor(pl[c], off);
      pr[c] += __shfl_xor(pr[c], off);
    }
  }
  if (L == 0) {
    float4 b0 = *(const float4*)(bl2);
    float4 b1 = *(const float4*)(br2);
    *(float4*)(xl2 + (size_t)node * 4) =
        make_float4(pl[0] + b0.x, pl[1] + b0.y, pl[2] + b0.z, pl[3] + b0.w);
    *(float4*)(xr2 + (size_t)node * 4) =
        make_float4(pr[0] + b1.x, pr[1] + b1.y, pr[2] + b1.z, pr[3] + b1.w);
  }
}

// ---------------------------------------------------------------- layer 2 attention + final softmax

__global__ __launch_bounds__(256) void agg2_kernel(
    const float* __restrict__ xl2, const float* __restrict__ xr2,
    const float* __restrict__ att, const float* __restrict__ bias,
    const int* __restrict__ degp, const unsigned short* __restrict__ ell,
    float* __restrict__ out) {
  int gid = blockIdx.x * 256 + threadIdx.x;
  int node = gid >> 4;
  if (node >= N_NODES) return;
  int L = threadIdx.x & 15;
  float4 xr = *(const float4*)(xr2 + (size_t)node * 4);
  float4 at = *(const float4*)(att);
  float m = -1e30f, denom = 0.f;
  float4 acc = make_float4(0.f, 0.f, 0.f, 0.f);
  int p1 = degp[node << 4];
  const unsigned short* erow = ell + (size_t)node * MAXD;
  int nit = (p1 + 15) >> 4;
  int p = L;
  for (int it = 0; it < nit; ++it) {
    bool valid = p < p1;
    int s = erow[valid ? p : p1 - 1];
    float4 xv = *(const float4*)(xl2 + (size_t)s * 4);
    float e0 = xv.x + xr.x; e0 = fmaxf(e0, 0.2f * e0);
    float e1 = xv.y + xr.y; e1 = fmaxf(e1, 0.2f * e1);
    float e2 = xv.z + xr.z; e2 = fmaxf(e2, 0.2f * e2);
    float e3 = xv.w + xr.w; e3 = fmaxf(e3, 0.2f * e3);
    float pa = e0 * at.x + e1 * at.y + e2 * at.z + e3 * at.w;
    pa = valid ? pa : -1e30f;
    float mnew  = fmaxf(m, pa);
    float scale = __expf(m - mnew);
    float wgt   = __expf(pa - mnew);    // exact 0 for padded slots
    denom = denom * scale + wgt;
    acc.x = acc.x * scale + wgt * xv.x;
    acc.y = acc.y * scale + wgt * xv.y;
    acc.z = acc.z * scale + wgt * xv.z;
    acc.w = acc.w * scale + wgt * xv.w;
    m = mnew;
    p += 16;
  }
  #pragma unroll
  for (int off = 1; off < 16; off <<= 1) {
    float mo = __shfl_xor(m, off);
    float dn = __shfl_xor(denom, off);
    float ax = __shfl_xor(acc.x, off);
    float ay = __shfl_xor(acc.y, off);
    float az = __shfl_xor(acc.z, off);
    float aw = __shfl_xor(acc.w, off);
    float mnew = fmaxf(m, mo);
    float sa = __expf(m - mnew);
    float sb = __expf(mo - mnew);
    denom = denom * sa + dn * sb;
    acc.x = acc.x * sa + ax * sb;
    acc.y = acc.y * sa + ay * sb;
    acc.z = acc.z * sa + az * sb;
    acc.w = acc.w * sa + aw * sb;
    m = mnew;
  }
  if (L == 0) {
    float inv = 1.f / (denom + 1e-16f);
    float4 b = *(const float4*)(bias);
    float o0 = acc.x * inv + b.x;
    float o1 = acc.y * inv + b.y;
    float o2 = acc.z * inv + b.z;
    float o3 = acc.w * inv + b.w;
    float mx = fmaxf(fmaxf(o0, o1), fmaxf(o2, o3));
    float q0 = __expf(o0 - mx), q1 = __expf(o1 - mx), q2 = __expf(o2 - mx), q3 = __expf(o3 - mx);
    float r = 1.f / (q0 + q1 + q2 + q3);
    *(float4*)(out + (size_t)node * 4) = make_float4(q0 * r, q1 * r, q2 * r, q3 * r);
  }
}

// ---------------------------------------------------------------- launch (4 dispatches total)

extern "C" void kernel_launch(void* const* d_in, const int* in_sizes, int n_in,
                              void* d_out, int out_size, void* d_ws, size_t ws_size,
                              hipStream_t stream) {
  (void)in_sizes; (void)n_in; (void)out_size; (void)ws_size;
  const float* x     = (const float*)d_in[0];
  const int*   ei    = (const int*)d_in[1];
  const float* Wl1   = (const float*)d_in[3];
  const float* bl1   = (const float*)d_in[4];
  const float* Wr1   = (const float*)d_in[5];
  const float* br1   = (const float*)d_in[6];
  const float* att1  = (const float*)d_in[7];
  const float* bias1 = (const float*)d_in[8];
  const float* Wl2   = (const float*)d_in[9];
  const float* bl2   = (const float*)d_in[10];
  const float* Wr2   = (const float*)d_in[11];
  const float* br2   = (const float*)d_in[12];
  const float* att2  = (const float*)d_in[13];
  const float* bias2 = (const float*)d_in[14];
  float* out = (float*)d_out;

  char* w = (char*)d_ws;
  auto alloc = [&](size_t bytes) -> char* {
    char* p = w;
    w += (bytes + 255) & ~(size_t)255;
    return p;
  };
  short*          xl1  = (short*)alloc((size_t)N_NODES * 128 * 2);
  short*          xr1  = (short*)alloc((size_t)N_NODES * 128 * 2);
  float*          xl2  = (float*)alloc((size_t)N_NODES * 4 * 4);
  float*          xr2  = (float*)alloc((size_t)N_NODES * 4 * 4);
  int*            degp = (int*)alloc((size_t)N_NODES * 16 * 4);   // one counter per 64B line
  unsigned short* ell  = (unsigned short*)alloc((size_t)N_NODES * MAXD * 2);
  short*          Wbf  = (short*)alloc((size_t)256 * 128 * 2);

  init_kernel<<<ZBLK + 16, 256, 0, stream>>>(degp, ell, Wl1, Wr1, Wbf);
  gemm_build<<<GBLK + NCLS * EBLK, 256, 0, stream>>>(x, Wbf, bl1, br1, xl1, xr1, ei, degp, ell);
  agg1_fused<<<(N_NODES * 16 + 255) / 256, 256, 0, stream>>>(
      xl1, xr1, att1, bias1, Wl2, bl2, Wr2, br2, degp, ell, xl2, xr2);
  agg2_kernel<<<(N_NODES * 16 + 255) / 256, 256, 0, stream>>>(
      xl2, xr2, att2, bias2, degp, ell, out);
}

// Round 19
// 123.590 us; speedup vs baseline: 1.1127x; 1.1127x over previous
//
#include <hip/hip_runtime.h>

#define N_NODES 50000
#define N_EDGES 600000
#define E_TOT   650000   // edges + self loops
#define EPT     4        // edges per scatter thread (independent atomic chains)
#define SBLK    586      // ceil(N_EDGES/(256*EPT)) scatter blocks
#define GBLK    391      // ceil(N_NODES/128) gemm blocks
#define ZBLK    196      // ceil(N_NODES/256) init blocks
#define MAXD    64       // ELL stride; max in-degree ~ Poisson(12)+1 << 64

typedef __attribute__((ext_vector_type(8))) short short8;
typedef __attribute__((ext_vector_type(4))) float f32x4;

__device__ inline short f2bf(float f) {           // round-to-nearest-even f32->bf16
  union { float f; unsigned u; } v; v.f = f;
  unsigned r = (v.u + 0x7FFFu + ((v.u >> 16) & 1u)) >> 16;
  return (short)r;
}
__device__ inline float bf2f(short u) {
  union { unsigned u; float f; } v; v.u = ((unsigned)(unsigned short)u) << 16;
  return v.f;
}

// ---------------------------------------------------------------- init: self-loop prefill + W prep (one launch)
// degp = line-padded counters. blocks [0, ZBLK): degp[i<<4]=1; ell[i*MAXD]=i.
// blocks [ZBLK, ZBLK+16): transpose-convert Wl1|Wr1 f32 [128k][128c] -> bf16 [256c][128k]

__global__ __launch_bounds__(256) void init_kernel(
    int* __restrict__ degp, unsigned short* __restrict__ ell,
    const float* __restrict__ Wl, const float* __restrict__ Wr, short* __restrict__ Wbf) {
  int b = blockIdx.x;
  if (b < ZBLK) {
    int i = b * 256 + threadIdx.x;
    if (i < N_NODES) {
      degp[i << 4] = 1;
      ell[i * MAXD] = (unsigned short)i;
    }
  } else {
    int gid = (b - ZBLK) * 256 + threadIdx.x;   // 4096 threads: 256 cols x 16 k-chunks
    int c = gid >> 4, k8 = (gid & 15) * 8;
    const float* W = (c < 128) ? Wl : Wr;
    int cc = c & 127;
    short8 o;
    #pragma unroll
    for (int j = 0; j < 8; ++j) o[j] = f2bf(W[(size_t)(k8 + j) * 128 + cc]);
    *(short8*)(Wbf + (size_t)c * 128 + k8) = o;
  }
}

// ---------------------------------------------------------------- layer 1 GEMM + ELL build, one launch
// blocks [0, GBLK): LDS-FREE MFMA GEMM (A in registers, B from L2-resident Wbf)
// blocks [GBLK, GBLK+SBLK): scatter, EPT=4 independent atomic chains per thread:
// 8 coalesced loads up front -> 4 independent fetch-adds -> 4 stores. Block
// covers 1024 edges (thread t handles base+t, +256, +512, +768: coalesced).

__global__ __launch_bounds__(256) void gemm_build(
    const float* __restrict__ x, const short* __restrict__ Wbf,
    const float* __restrict__ bl, const float* __restrict__ br,
    short* __restrict__ xl, short* __restrict__ xr,
    const int* __restrict__ ei, int* __restrict__ degp, unsigned short* __restrict__ ell) {
  int t = threadIdx.x;

  if (blockIdx.x >= GBLK) {            // ---- batched edge scatter (no LDS)
    int base = (blockIdx.x - GBLK) * (256 * EPT) + t;
    int e[EPT], s[EPT], d[EPT];
    #pragma unroll
    for (int j = 0; j < EPT; ++j) {
      e[j] = base + j * 256;
      bool v = e[j] < N_EDGES;
      int ec = v ? e[j] : N_EDGES - 1;
      s[j] = ei[ec];                   // 8 independent coalesced loads
      d[j] = ei[N_EDGES + ec];
      if (!v) d[j] = -1;
    }
    int pos[EPT];
    #pragma unroll
    for (int j = 0; j < EPT; ++j)      // 4 independent fetch-adds in flight
      pos[j] = (d[j] >= 0) ? atomicAdd(&degp[d[j] << 4], 1) : 0;
    #pragma unroll
    for (int j = 0; j < EPT; ++j)
      if (d[j] >= 0) ell[d[j] * MAXD + pos[j]] = (unsigned short)s[j];
    return;
  }

  // ---- GEMM part
  int row0 = blockIdx.x * 128;
  int w = t >> 6, lane = t & 63;
  int wm = (w >> 1) * 64, wn = (w & 1) * 64;
  int lr = lane & 15, lk = (lane >> 4) * 8;

  // A fragments: rows wm+m*16+lr, k = ks*32+lk..+8, f32 -> bf16 inline.
  short8 af[4][4];                     // [ks][m]
  #pragma unroll
  for (int ks = 0; ks < 4; ++ks) {
    #pragma unroll
    for (int m = 0; m < 4; ++m) {
      int gr = row0 + wm + m * 16 + lr;
      gr = gr < N_NODES ? gr : N_NODES - 1;
      const float* p = x + (size_t)gr * 128 + ks * 32 + lk;
      f32x4 a = *(const f32x4*)p, b = *(const f32x4*)(p + 4);
      short8 o;
      o[0] = f2bf(a.x); o[1] = f2bf(a.y); o[2] = f2bf(a.z); o[3] = f2bf(a.w);
      o[4] = f2bf(b.x); o[5] = f2bf(b.y); o[6] = f2bf(b.z); o[7] = f2bf(b.w);
      af[ks][m] = o;
    }
  }

  #pragma unroll
  for (int hb = 0; hb < 2; ++hb) {
    f32x4 acc[4][4];
    #pragma unroll
    for (int m = 0; m < 4; ++m)
      #pragma unroll
      for (int n = 0; n < 4; ++n) acc[m][n] = (f32x4){0.f, 0.f, 0.f, 0.f};

    #pragma unroll
    for (int ks = 0; ks < 4; ++ks) {
      short8 bfr[4];
      #pragma unroll
      for (int n = 0; n < 4; ++n) {
        int col = hb * 128 + wn + n * 16 + lr;
        bfr[n] = *(const short8*)(Wbf + (size_t)col * 128 + ks * 32 + lk);
      }
      #pragma unroll
      for (int m = 0; m < 4; ++m)
        #pragma unroll
        for (int n = 0; n < 4; ++n)
          acc[m][n] = __builtin_amdgcn_mfma_f32_16x16x32_bf16(af[ks][m], bfr[n], acc[m][n], 0, 0, 0);
    }

    const float* B0 = hb ? br : bl;
    short* O = hb ? xr : xl;
    int orow = (lane >> 4) * 4;
    #pragma unroll
    for (int n = 0; n < 4; ++n) {
      int col = wn + n * 16 + lr;
      float bv = B0[col];
      #pragma unroll
      for (int m = 0; m < 4; ++m) {
        #pragma unroll
        for (int r = 0; r < 4; ++r) {
          int grow = row0 + wm + m * 16 + orow + r;
          if (grow < N_NODES) O[(size_t)grow * 128 + col] = f2bf(acc[m][n][r] + bv);
        }
      }
    }
  }
}

// ---------------------------------------------------------------- layer 1 attention+aggregation fused with layer-2 GEMV
// 16 lanes per node. Per 8-edge tile: gathers go global->LDS via
// global_load_lds (per-lane global addr, wave-uniform LDS dest, zero VGPR for
// in-flight rows). Wave-private LDS slots: no __syncthreads, just vmcnt.

__global__ __launch_bounds__(256) void agg1_fused(
    const short* __restrict__ xl1, const short* __restrict__ xr1,
    const float* __restrict__ att, const float* __restrict__ bias,
    const float* __restrict__ Wl2, const float* __restrict__ bl2,
    const float* __restrict__ Wr2, const float* __restrict__ br2,
    const int* __restrict__ degp, const unsigned short* __restrict__ ell,
    float* __restrict__ xl2, float* __restrict__ xr2) {
  __shared__ short sbuf[4][8][512];    // [wave][slot][64 lanes x 8 shorts] = 32 KB
  int gid = blockIdx.x * 256 + threadIdx.x;
  int node = gid >> 4;                 // grid exact: 3125 blocks * 16 nodes
  int t = threadIdx.x;
  int wid = t >> 6, lane = t & 63;
  int L = lane & 15;
  int gbase = lane & 48;               // wave-lane base of this 16-lane group

  short8 xr8 = *(const short8*)(xr1 + (size_t)node * 128 + L * 8);
  float xr[8], at[8];
  #pragma unroll
  for (int r = 0; r < 8; ++r) xr[r] = bf2f(xr8[r]);
  *(float4*)(at)     = *(const float4*)(att + L * 8);
  *(float4*)(at + 4) = *(const float4*)(att + L * 8 + 4);

  float m = -1e30f, denom = 0.f;
  float acc[8];
  #pragma unroll
  for (int r = 0; r < 8; ++r) acc[r] = 0.f;

  int p1 = degp[node << 4];
  const unsigned short* erow = ell + (size_t)node * MAXD;

  for (int base = 0; base < p1; base += 8) {
    // ONE coalesced index load: lane L holds edge (base+L)'s src for its node
    int pE = base + L;
    int myidx = erow[pE < p1 ? pE : p1 - 1];
    // 8 gathers global->LDS, all in flight, zero VGPR held
    #pragma unroll
    for (int j = 0; j < 8; ++j) {
      int ij = __shfl(myidx, gbase + j);
      const short* gp = xl1 + (size_t)ij * 128 + L * 8;
      __builtin_amdgcn_global_load_lds(
          (const __attribute__((address_space(1))) void*)gp,
          (__attribute__((address_space(3))) void*)&sbuf[wid][j][0],
          16, 0, 0);
    }
    asm volatile("s_waitcnt vmcnt(0)" ::: "memory");
    __builtin_amdgcn_sched_barrier(0);

    // 8 alpha dots (read own 16B slice back from LDS)
    float pa[8];
    #pragma unroll
    for (int j = 0; j < 8; ++j) {
      short8 v = *(const short8*)(&sbuf[wid][j][lane * 8]);
      float s = 0.f;
      #pragma unroll
      for (int r = 0; r < 8; ++r) {
        float e = bf2f(v[r]) + xr[r];
        e = fmaxf(e, 0.2f * e);          // leaky_relu 0.2, exact
        s = fmaf(e, at[r], s);
      }
      pa[j] = s;
    }
    // pipelined shuffle reductions (24 independent DS ops)
    #pragma unroll
    for (int st = 1; st < 8; st <<= 1) {
      #pragma unroll
      for (int j = 0; j < 8; ++j) pa[j] += __shfl_xor(pa[j], st);
    }
    // mask padded slots branchlessly (exp underflows to exact 0)
    #pragma unroll
    for (int j = 0; j < 8; ++j) pa[j] = (base + j < p1) ? pa[j] : -1e30f;
    // ONE online-softmax fold per tile
    float bm = pa[0];
    #pragma unroll
    for (int j = 1; j < 8; ++j) bm = fmaxf(bm, pa[j]);
    float mnew  = fmaxf(m, bm);
    float scale = __expf(m - mnew);
    float wgt[8], dsum = 0.f;
    #pragma unroll
    for (int j = 0; j < 8; ++j) { wgt[j] = __expf(pa[j] - mnew); dsum += wgt[j]; }
    denom = denom * scale + dsum;
    #pragma unroll
    for (int r = 0; r < 8; ++r) acc[r] *= scale;
    #pragma unroll
    for (int j = 0; j < 8; ++j) {
      short8 v = *(const short8*)(&sbuf[wid][j][lane * 8]);
      #pragma unroll
      for (int r = 0; r < 8; ++r) acc[r] = fmaf(wgt[j], bf2f(v[r]), acc[r]);
    }
    m = mnew;
  }

  float inv = 1.f / (denom + 1e-16f);
  float o[8];
  #pragma unroll
  for (int r = 0; r < 8; ++r) {
    float v = acc[r] * inv + bias[L * 8 + r];
    o[r] = fmaxf(v, 0.01f * v);         // post-layer LeakyReLU(0.01), exact
  }
  // fused layer-2 linear: lane L holds h[L*8 .. L*8+7]
  float pl[4] = {0.f, 0.f, 0.f, 0.f}, pr[4] = {0.f, 0.f, 0.f, 0.f};
  #pragma unroll
  for (int r = 0; r < 8; ++r) {
    float4 wl = *(const float4*)(Wl2 + (size_t)(L * 8 + r) * 4);
    float4 wr = *(const float4*)(Wr2 + (size_t)(L * 8 + r) * 4);
    pl[0] += o[r] * wl.x;  pl[1] += o[r] * wl.y;  pl[2] += o[r] * wl.z;  pl[3] += o[r] * wl.w;
    pr[0] += o[r] * wr.x;  pr[1] += o[r] * wr.y;  pr[2] += o[r] * wr.z;  pr[3] += o[r] * wr.w;
  }
  #pragma unroll
  for (int off = 1; off < 16; off <<= 1) {
    #pragma unroll
    for (int c = 0; c < 4; ++c) {
      pl[c] += __shfl_xor(pl[c], off);
      pr[c] += __shfl_xor(pr[c], off);
    }
  }
  if (L == 0) {
    float4 b0 = *(const float4*)(bl2);
    float4 b1 = *(const float4*)(br2);
    *(float4*)(xl2 + (size_t)node * 4) =
        make_float4(pl[0] + b0.x, pl[1] + b0.y, pl[2] + b0.z, pl[3] + b0.w);
    *(float4*)(xr2 + (size_t)node * 4) =
        make_float4(pr[0] + b1.x, pr[1] + b1.y, pr[2] + b1.z, pr[3] + b1.w);
  }
}

// ---------------------------------------------------------------- layer 2 attention + final softmax

__global__ __launch_bounds__(256) void agg2_kernel(
    const float* __restrict__ xl2, const float* __restrict__ xr2,
    const float* __restrict__ att, const float* __restrict__ bias,
    const int* __restrict__ degp, const unsigned short* __restrict__ ell,
    float* __restrict__ out) {
  int gid = blockIdx.x * 256 + threadIdx.x;
  int node = gid >> 4;
  if (node >= N_NODES) return;
  int L = threadIdx.x & 15;
  float4 xr = *(const float4*)(xr2 + (size_t)node * 4);
  float4 at = *(const float4*)(att);
  float m = -1e30f, denom = 0.f;
  float4 acc = make_float4(0.f, 0.f, 0.f, 0.f);
  int p1 = degp[node << 4];
  const unsigned short* erow = ell + (size_t)node * MAXD;
  int nit = (p1 + 15) >> 4;
  int p = L;
  for (int it = 0; it < nit; ++it) {
    bool valid = p < p1;
    int s = erow[valid ? p : p1 - 1];
    float4 xv = *(const float4*)(xl2 + (size_t)s * 4);
    float e0 = xv.x + xr.x; e0 = fmaxf(e0, 0.2f * e0);
    float e1 = xv.y + xr.y; e1 = fmaxf(e1, 0.2f * e1);
    float e2 = xv.z + xr.z; e2 = fmaxf(e2, 0.2f * e2);
    float e3 = xv.w + xr.w; e3 = fmaxf(e3, 0.2f * e3);
    float pa = e0 * at.x + e1 * at.y + e2 * at.z + e3 * at.w;
    pa = valid ? pa : -1e30f;
    float mnew  = fmaxf(m, pa);
    float scale = __expf(m - mnew);
    float wgt   = __expf(pa - mnew);    // exact 0 for padded slots
    denom = denom * scale + wgt;
    acc.x = acc.x * scale + wgt * xv.x;
    acc.y = acc.y * scale + wgt * xv.y;
    acc.z = acc.z * scale + wgt * xv.z;
    acc.w = acc.w * scale + wgt * xv.w;
    m = mnew;
    p += 16;
  }
  #pragma unroll
  for (int off = 1; off < 16; off <<= 1) {
    float mo = __shfl_xor(m, off);
    float dn = __shfl_xor(denom, off);
    float ax = __shfl_xor(acc.x, off);
    float ay = __shfl_xor(acc.y, off);
    float az = __shfl_xor(acc.z, off);
    float aw = __shfl_xor(acc.w, off);
    float mnew = fmaxf(m, mo);
    float sa = __expf(m - mnew);
    float sb = __expf(mo - mnew);
    denom = denom * sa + dn * sb;
    acc.x = acc.x * sa + ax * sb;
    acc.y = acc.y * sa + ay * sb;
    acc.z = acc.z * sa + az * sb;
    acc.w = acc.w * sa + aw * sb;
    m = mnew;
  }
  if (L == 0) {
    float inv = 1.f / (denom + 1e-16f);
    float4 b = *(const float4*)(bias);
    float o0 = acc.x * inv + b.x;
    float o1 = acc.y * inv + b.y;
    float o2 = acc.z * inv + b.z;
    float o3 = acc.w * inv + b.w;
    float mx = fmaxf(fmaxf(o0, o1), fmaxf(o2, o3));
    float q0 = __expf(o0 - mx), q1 = __expf(o1 - mx), q2 = __expf(o2 - mx), q3 = __expf(o3 - mx);
    float r = 1.f / (q0 + q1 + q2 + q3);
    *(float4*)(out + (size_t)node * 4) = make_float4(q0 * r, q1 * r, q2 * r, q3 * r);
  }
}

// ---------------------------------------------------------------- launch (4 dispatches total)

extern "C" void kernel_launch(void* const* d_in, const int* in_sizes, int n_in,
                              void* d_out, int out_size, void* d_ws, size_t ws_size,
                              hipStream_t stream) {
  (void)in_sizes; (void)n_in; (void)out_size; (void)ws_size;
  const float* x     = (const float*)d_in[0];
  const int*   ei    = (const int*)d_in[1];
  const float* Wl1   = (const float*)d_in[3];
  const float* bl1   = (const float*)d_in[4];
  const float* Wr1   = (const float*)d_in[5];
  const float* br1   = (const float*)d_in[6];
  const float* att1  = (const float*)d_in[7];
  const float* bias1 = (const float*)d_in[8];
  const float* Wl2   = (const float*)d_in[9];
  const float* bl2   = (const float*)d_in[10];
  const float* Wr2   = (const float*)d_in[11];
  const float* br2   = (const float*)d_in[12];
  const float* att2  = (const float*)d_in[13];
  const float* bias2 = (const float*)d_in[14];
  float* out = (float*)d_out;

  char* w = (char*)d_ws;
  auto alloc = [&](size_t bytes) -> char* {
    char* p = w;
    w += (bytes + 255) & ~(size_t)255;
    return p;
  };
  short*          xl1  = (short*)alloc((size_t)N_NODES * 128 * 2);
  short*          xr1  = (short*)alloc((size_t)N_NODES * 128 * 2);
  float*          xl2  = (float*)alloc((size_t)N_NODES * 4 * 4);
  float*          xr2  = (float*)alloc((size_t)N_NODES * 4 * 4);
  int*            degp = (int*)alloc((size_t)N_NODES * 16 * 4);   // one counter per 64B line
  unsigned short* ell  = (unsigned short*)alloc((size_t)N_NODES * MAXD * 2);
  short*          Wbf  = (short*)alloc((size_t)256 * 128 * 2);

  init_kernel<<<ZBLK + 16, 256, 0, stream>>>(degp, ell, Wl1, Wr1, Wbf);
  gemm_build<<<GBLK + SBLK, 256, 0, stream>>>(x, Wbf, bl1, br1, xl1, xr1, ei, degp, ell);
  agg1_fused<<<(N_NODES * 16 + 255) / 256, 256, 0, stream>>>(
      xl1, xr1, att1, bias1, Wl2, bl2, Wr2, br2, degp, ell, xl2, xr2);
  agg2_kernel<<<(N_NODES * 16 + 255) / 256, 256, 0, stream>>>(
      xl2, xr2, att2, bias2, degp, ell, out);
}